// Round 9
// baseline (990.216 us; speedup 1.0000x reference)
//
#include <hip/hip_runtime.h>
#include <math.h>

#define Bb 16
#define Nn 100
#define Ll 90
#define Dd 300
#define NBLK (Bb*Nn)
#define LP 96
#define DP 320
#define DPH 40   // DP/8 16-byte chunks per row

typedef __attribute__((ext_vector_type(8))) short short8v;
typedef __attribute__((ext_vector_type(4))) short short4v;
typedef __attribute__((ext_vector_type(4))) float f32x4;

__device__ __forceinline__ unsigned short f2bf(float f) {
  unsigned int u = __float_as_uint(f);
  u += 0x7fffu + ((u >> 16) & 1u);
  return (unsigned short)(u >> 16);
}
__device__ __forceinline__ float bf2f(unsigned short h) {
  return __uint_as_float(((unsigned int)h) << 16);
}

// ---------------- fused setup ----------------
__global__ __launch_bounds__(256) void k_setup(
    const float* __restrict__ Wq, const float* __restrict__ Wk,
    const float* __restrict__ bq, const float* __restrict__ bk,
    const float* __restrict__ Wf, const float* __restrict__ Wv,
    const float* __restrict__ bv, const float* __restrict__ bf,
    unsigned short* __restrict__ Mb, float* __restrict__ G,
    float* __restrict__ bias2) {
  int blk = blockIdx.x;
  if (blk < 400) {
    int idx = blk * 256 + threadIdx.x;
    int i = idx / DP, j = idx % DP;
    float s = 0.f;
    if (i <= Dd && j <= Dd) {
#pragma unroll 10
      for (int o = 0; o < Dd; o++) {
        float av = (i < Dd) ? Wq[o * Dd + i] : bq[o];
        float bw = (j < Dd) ? Wk[o * Dd + j] : bk[o];
        s += av * bw;
      }
    }
    Mb[idx] = f2bf(s);
  } else if (blk < 757) {
    int idx = (blk - 400) * 256 + threadIdx.x;
    if (idx < Dd * 304) {
      int o = idx / 304, p = idx % 304;
      float s = 0.f;
      if (p < Dd) {
#pragma unroll 10
        for (int v = 0; v < Dd; v++) s += Wf[o * Dd + v] * Wv[v * Dd + p];
      }
      G[idx] = s;
    }
  } else {
    for (int t = threadIdx.x; t < 304; t += 256) {
      float sb = 0.f;
      if (t < Dd) {
#pragma unroll 10
        for (int v = 0; v < Dd; v++) sb += Wf[t * Dd + v] * bv[v];
        sb = 90.f * (sb + bf[t]);
      }
      bias2[t] = sb;
    }
  }
}

// C[z] = A[z] * B[z] (256x256 each), optional column scale
__global__ __launch_bounds__(256) void k_mm256(
    const float* __restrict__ A0, const float* __restrict__ A1, int lda,
    const float* __restrict__ B0, const float* __restrict__ B1, int ldb,
    float* __restrict__ C, int ldc, const float* __restrict__ gamma) {
  const float* A = blockIdx.z ? A1 : A0;
  const float* B = blockIdx.z ? B1 : B0;
  float* Cb = C + (size_t)blockIdx.z * 256 * ldc;
  __shared__ float As[16][68];
  __shared__ float Bs[16][68];
  int m0 = blockIdx.x * 64, n0 = blockIdx.y * 64;
  int tx = threadIdx.x & 15, ty = threadIdx.x >> 4;
  float acc[4][4];
#pragma unroll
  for (int i = 0; i < 4; i++)
#pragma unroll
    for (int j = 0; j < 4; j++) acc[i][j] = 0.f;
  int r = threadIdx.x >> 2;
  int kq = (threadIdx.x & 3) << 2;
  int kk2 = threadIdx.x >> 4;
  int nq = (threadIdx.x & 15) << 2;
  for (int k0 = 0; k0 < 256; k0 += 16) {
    {
      float4 v = *(const float4*)(A + (size_t)(m0 + r) * lda + k0 + kq);
      As[kq + 0][r] = v.x; As[kq + 1][r] = v.y; As[kq + 2][r] = v.z; As[kq + 3][r] = v.w;
    }
    {
      float4 v = *(const float4*)(B + (size_t)(k0 + kk2) * ldb + n0 + nq);
      Bs[kk2][nq + 0] = v.x; Bs[kk2][nq + 1] = v.y; Bs[kk2][nq + 2] = v.z; Bs[kk2][nq + 3] = v.w;
    }
    __syncthreads();
#pragma unroll
    for (int kk = 0; kk < 16; kk++) {
      float4 av = *(const float4*)&As[kk][ty * 4];
      float4 bv = *(const float4*)&Bs[kk][tx * 4];
      acc[0][0] += av.x * bv.x; acc[0][1] += av.x * bv.y; acc[0][2] += av.x * bv.z; acc[0][3] += av.x * bv.w;
      acc[1][0] += av.y * bv.x; acc[1][1] += av.y * bv.y; acc[1][2] += av.y * bv.z; acc[1][3] += av.y * bv.w;
      acc[2][0] += av.z * bv.x; acc[2][1] += av.z * bv.y; acc[2][2] += av.z * bv.z; acc[2][3] += av.z * bv.w;
      acc[3][0] += av.w * bv.x; acc[3][1] += av.w * bv.y; acc[3][2] += av.w * bv.z; acc[3][3] += av.w * bv.w;
    }
    __syncthreads();
  }
  const float bninv = rsqrtf(1.00001f);
#pragma unroll
  for (int i = 0; i < 4; i++) {
    int gm = m0 + ty * 4 + i;
#pragma unroll
    for (int j = 0; j < 4; j++) {
      int gn = n0 + tx * 4 + j;
      float v = acc[i][j];
      if (gamma) v *= gamma[gn] * bninv;
      Cb[(size_t)gm * ldc + gn] = v;
    }
  }
}

__global__ __launch_bounds__(256) void k_vecd(
    const float* __restrict__ W_fc, const float* __restrict__ b_fc,
    const float* __restrict__ beta,
    const float* __restrict__ W_in, const float* __restrict__ b_in,
    const float* __restrict__ b_iah,
    const float* __restrict__ W_out, const float* __restrict__ b_out,
    const float* __restrict__ b_oah,
    const float* __restrict__ W_io, const float* __restrict__ b_io,
    float* __restrict__ dvec) {
  __shared__ float v1[256];
  __shared__ float v23[512];
  int i = threadIdx.x;
  float s = 0.f;
#pragma unroll 16
  for (int k = 0; k < 256; k++) s += W_fc[i * 256 + k] * beta[k];
  v1[i] = s + b_fc[i];
  __syncthreads();
  float s2 = 0.f, s3 = 0.f;
#pragma unroll 16
  for (int k = 0; k < 256; k++) {
    float vk = v1[k];
    s2 += W_in[i * 256 + k] * vk;
    s3 += W_out[i * 256 + k] * vk;
  }
  v23[i] = s2 + b_in[i] + b_iah[i];
  v23[256 + i] = s3 + b_out[i] + b_oah[i];
  __syncthreads();
  float sd = 0.f;
#pragma unroll 16
  for (int k = 0; k < 512; k++) sd += W_io[i * 512 + k] * v23[k];
  dvec[i] = sd + b_io[i];
}

// ---------------- k_zt: ZT[bn][m][i] = sum_j M'[i][j] X'[bn][m][j] (bf16) ----------------
// One barrier; G1-only; colsum at the end (independent of LDS).
__global__ __launch_bounds__(512, 4) void k_zt(
    const float* __restrict__ items, const unsigned short* __restrict__ Mb,
    unsigned short* __restrict__ ZT, float* __restrict__ colsum_all) {
  __shared__ unsigned short Xs[LP * DP];   // 61440 B
  const int tid = threadIdx.x;
  const int bid = blockIdx.x;
  const float* Xg = items + (size_t)bid * (Ll * Dd);

  // stage X' -> LDS bf16 swizzled [96][320], col 300 = 1.0
  for (int c = tid; c < LP * DPH; c += 512) {
    int l = c / DPH, ch = c % DPH, d0 = ch * 8;
    float v[8];
    if (l < Ll && d0 < Dd) {
      if (d0 + 8 <= Dd) {
        float4 a = *(const float4*)(Xg + l * Dd + d0);
        float4 b = *(const float4*)(Xg + l * Dd + d0 + 4);
        v[0] = a.x; v[1] = a.y; v[2] = a.z; v[3] = a.w;
        v[4] = b.x; v[5] = b.y; v[6] = b.z; v[7] = b.w;
      } else {
#pragma unroll
        for (int q = 0; q < 8; q++) {
          int d = d0 + q;
          v[q] = (d < Dd) ? Xg[l * Dd + d] : ((d == Dd) ? 1.f : 0.f);
        }
      }
    } else {
#pragma unroll
      for (int q = 0; q < 8; q++) v[q] = 0.f;
    }
    short8v pk;
#pragma unroll
    for (int q = 0; q < 8; q++) pk[q] = (short)f2bf(v[q]);
    *(short8v*)((char*)Xs + l * 640 + ((d0 * 2) ^ ((l & 7) << 4))) = pk;
  }
  __syncthreads();

  const int lane = tid & 63, wave = tid >> 6;
  const int fr = lane & 15, kg = lane >> 4;
  unsigned short* ZTb = ZT + (size_t)bid * (LP * DP);

  for (int t = wave; t < 20; t += 8) {
    f32x4 z[6];
#pragma unroll
    for (int mt = 0; mt < 6; mt++) z[mt] = (f32x4){0.f, 0.f, 0.f, 0.f};
    const unsigned short* Ma = Mb + (size_t)(t * 16 + fr) * DP;
#pragma unroll
    for (int ks = 0; ks < 10; ks++) {
      int koff = ks * 32 + kg * 8;
      short8v a = *(const short8v*)(Ma + koff);
#pragma unroll
      for (int mt = 0; mt < 6; mt++) {
        int brow = mt * 16 + fr;
        short8v b = *(const short8v*)((char*)Xs + brow * 640 +
                                      ((koff * 2) ^ ((brow & 7) << 4)));
        z[mt] = __builtin_amdgcn_mfma_f32_16x16x32_bf16(a, b, z[mt], 0, 0, 0);
      }
    }
#pragma unroll
    for (int mt = 0; mt < 6; mt++) {
      int m = mt * 16 + fr;
      short4v pk;
#pragma unroll
      for (int r2 = 0; r2 < 4; r2++) pk[r2] = (short)f2bf(z[mt][r2]);
      *(short4v*)(ZTb + (size_t)m * DP + t * 16 + kg * 4) = pk;
    }
  }

  // colsum (exact f32, off the MFMA critical path)
  for (int d = tid; d < 304; d += 512) {
    float s = 0.f;
    if (d < Dd) {
#pragma unroll 18
      for (int l = 0; l < Ll; l++) s += Xg[l * Dd + d];
    }
    colsum_all[(size_t)bid * 304 + d] = s;
  }
}

// ---------------- k_attn2: S=X'.ZT^T (regs) -> softmax -> r ----------------
// 384 threads = 6 waves, wave w owns l-tile w. No LDS staging.
__global__ __launch_bounds__(384, 4) void k_attn2(
    const float* __restrict__ items, const unsigned short* __restrict__ ZT,
    float* __restrict__ r_all) {
  __shared__ float wsum[LP];
  const int tid = threadIdx.x;
  const int bid = blockIdx.x;
  const int lane = tid & 63, wave = tid >> 6;
  const int fr = lane & 15, kg = lane >> 4;
  if (tid < LP) wsum[tid] = 0.f;
  __syncthreads();

  const float* Xg = items + (size_t)bid * (Ll * Dd);
  const unsigned short* ZTb = ZT + (size_t)bid * (LP * DP);

  f32x4 acc[6];
#pragma unroll
  for (int mt = 0; mt < 6; mt++) acc[mt] = (f32x4){0.f, 0.f, 0.f, 0.f};

  const int l = wave * 16 + fr;
  const bool lval = l < Ll;
  const float* Xrow = Xg + (size_t)l * Dd;

#pragma unroll
  for (int ks = 0; ks < 10; ks++) {
    int k0 = ks * 32 + kg * 8;
    short8v a;
    if (lval && k0 + 8 <= Dd) {
      float4 f0 = *(const float4*)(Xrow + k0);
      float4 f1 = *(const float4*)(Xrow + k0 + 4);
      a[0] = (short)f2bf(f0.x); a[1] = (short)f2bf(f0.y);
      a[2] = (short)f2bf(f0.z); a[3] = (short)f2bf(f0.w);
      a[4] = (short)f2bf(f1.x); a[5] = (short)f2bf(f1.y);
      a[6] = (short)f2bf(f1.z); a[7] = (short)f2bf(f1.w);
    } else if (lval && k0 < Dd) {   // k0==296: last 4 real + the 1.0 column
      float4 f0 = *(const float4*)(Xrow + k0);
      a[0] = (short)f2bf(f0.x); a[1] = (short)f2bf(f0.y);
      a[2] = (short)f2bf(f0.z); a[3] = (short)f2bf(f0.w);
      a[4] = (short)0x3F80; a[5] = 0; a[6] = 0; a[7] = 0;
    } else {
#pragma unroll
      for (int q = 0; q < 8; q++) a[q] = 0;
    }
#pragma unroll
    for (int mt = 0; mt < 6; mt++) {
      int brow = mt * 16 + fr;
      short8v b = *(const short8v*)(ZTb + (size_t)brow * DP + k0);
      acc[mt] = __builtin_amdgcn_mfma_f32_16x16x32_bf16(a, b, acc[mt], 0, 0, 0);
    }
  }

  // in-register row softmax + column sums
  {
    float colpart[6] = {0.f, 0.f, 0.f, 0.f, 0.f, 0.f};
#pragma unroll
    for (int r2 = 0; r2 < 4; r2++) {
      int lr = wave * 16 + kg * 4 + r2;
      float x[6];
#pragma unroll
      for (int mt = 0; mt < 6; mt++) {
        int col = mt * 16 + fr;
        x[mt] = (col < Ll) ? 0.1f * acc[mt][r2] : -INFINITY;
      }
      float mx = x[0];
#pragma unroll
      for (int mt = 1; mt < 6; mt++) mx = fmaxf(mx, x[mt]);
      mx = fmaxf(mx, __shfl_xor(mx, 1));
      mx = fmaxf(mx, __shfl_xor(mx, 2));
      mx = fmaxf(mx, __shfl_xor(mx, 4));
      mx = fmaxf(mx, __shfl_xor(mx, 8));
      float e[6]; float s = 0.f;
#pragma unroll
      for (int mt = 0; mt < 6; mt++) { e[mt] = __expf(x[mt] - mx); s += e[mt]; }
      s += __shfl_xor(s, 1); s += __shfl_xor(s, 2);
      s += __shfl_xor(s, 4); s += __shfl_xor(s, 8);
      float inv = 1.f / s;
      if (lr < Ll) {
#pragma unroll
        for (int mt = 0; mt < 6; mt++) colpart[mt] += e[mt] * inv;
      }
    }
#pragma unroll
    for (int mt = 0; mt < 6; mt++) {
      colpart[mt] += __shfl_xor(colpart[mt], 16);
      colpart[mt] += __shfl_xor(colpart[mt], 32);
    }
    if (lane < 16) {
#pragma unroll
      for (int mt = 0; mt < 6; mt++) atomicAdd(&wsum[mt * 16 + fr], colpart[mt]);
    }
  }
  __syncthreads();

  // r[i] = sum_m wsum[m] X[m][i]  (exact f32 from global)
  for (int i = tid; i < 304; i += 384) {
    float s = 0.f;
    if (i < Dd) {
#pragma unroll 15
      for (int m = 0; m < Ll; m++) s += wsum[m] * Xg[(size_t)m * Dd + i];
    }
    r_all[(size_t)bid * 304 + i] = s;
  }
}

// ---------------- fallback fused k_attn (ws too small for ZT) ----------------
__global__ __launch_bounds__(512, 4) void k_attn(
    const float* __restrict__ items, const unsigned short* __restrict__ Mb,
    float* __restrict__ r_all, float* __restrict__ colsum_all) {
  __shared__ unsigned short Xs[LP * DP];
  __shared__ unsigned short Zc[LP * 64];
  __shared__ float wsum[LP];
  const int tid = threadIdx.x;
  const int bid = blockIdx.x;
  const float* Xg = items + (size_t)bid * (Ll * Dd);
  if (tid < LP) wsum[tid] = 0.f;
  for (int c = tid; c < LP * DPH; c += 512) {
    int l = c / DPH, ch = c % DPH, d0 = ch * 8;
    float v[8];
    if (l < Ll && d0 < Dd) {
      if (d0 + 8 <= Dd) {
        float4 a = *(const float4*)(Xg + l * Dd + d0);
        float4 b = *(const float4*)(Xg + l * Dd + d0 + 4);
        v[0] = a.x; v[1] = a.y; v[2] = a.z; v[3] = a.w;
        v[4] = b.x; v[5] = b.y; v[6] = b.z; v[7] = b.w;
      } else {
#pragma unroll
        for (int q = 0; q < 8; q++) {
          int d = d0 + q;
          v[q] = (d < Dd) ? Xg[l * Dd + d] : ((d == Dd) ? 1.f : 0.f);
        }
      }
    } else {
#pragma unroll
      for (int q = 0; q < 8; q++) v[q] = 0.f;
    }
    short8v pk;
#pragma unroll
    for (int q = 0; q < 8; q++) pk[q] = (short)f2bf(v[q]);
    *(short8v*)((char*)Xs + l * 640 + ((d0 * 2) ^ ((l & 7) << 4))) = pk;
  }
  for (int d = tid; d < 304; d += 512) {
    float s = 0.f;
    if (d < Dd) {
#pragma unroll 18
      for (int l = 0; l < Ll; l++) s += Xg[l * Dd + d];
    }
    colsum_all[(size_t)bid * 304 + d] = s;
  }
  __syncthreads();
  const int lane = tid & 63, wave = tid >> 6;
  const int fr = lane & 15, kg = lane >> 4;
  f32x4 acc[6];
#pragma unroll
  for (int mt = 0; mt < 6; mt++) acc[mt] = (f32x4){0.f, 0.f, 0.f, 0.f};
  for (int c = 0; c < 5; c++) {
    for (int t = wave; t < 24; t += 8) {
      int ict = t / 6, mt = t - ict * 6;
      int irow = c * 64 + ict * 16 + fr;
      f32x4 zacc = (f32x4){0.f, 0.f, 0.f, 0.f};
#pragma unroll
      for (int ks = 0; ks < 10; ks++) {
        int koff = ks * 32 + kg * 8;
        short8v a = *(const short8v*)(Mb + (size_t)irow * DP + koff);
        int brow = mt * 16 + fr;
        short8v b = *(const short8v*)((char*)Xs + brow * 640 +
                                      ((koff * 2) ^ ((brow & 7) << 4)));
        zacc = __builtin_amdgcn_mfma_f32_16x16x32_bf16(a, b, zacc, 0, 0, 0);
      }
      int m = mt * 16 + fr;
      int ic0 = ict * 16 + kg * 4;
      short4v pk;
#pragma unroll
      for (int r2 = 0; r2 < 4; r2++) pk[r2] = (short)f2bf(zacc[r2]);
      *(short4v*)((char*)Zc + m * 128 + ((ic0 * 2) ^ ((m & 7) << 4))) = pk;
    }
    __syncthreads();
    if (wave < 6) {
      int arow = wave * 16 + fr;
      int abyte = arow * 640, aswz = (arow & 7) << 4;
#pragma unroll
      for (int mt = 0; mt < 6; mt++) {
        int brow = mt * 16 + fr;
#pragma unroll
        for (int ks = 0; ks < 2; ks++) {
          short8v a = *(const short8v*)((char*)Xs + abyte +
                                        (((c * 64 + ks * 32 + kg * 8) * 2) ^ aswz));
          short8v b = *(const short8v*)((char*)Zc + brow * 128 +
                                        (((ks * 32 + kg * 8) * 2) ^ ((brow & 7) << 4)));
          acc[mt] = __builtin_amdgcn_mfma_f32_16x16x32_bf16(a, b, acc[mt], 0, 0, 0);
        }
      }
    }
    __syncthreads();
  }
  if (wave < 6) {
    float colpart[6] = {0.f, 0.f, 0.f, 0.f, 0.f, 0.f};
#pragma unroll
    for (int r2 = 0; r2 < 4; r2++) {
      int l = wave * 16 + kg * 4 + r2;
      float x[6];
#pragma unroll
      for (int mt = 0; mt < 6; mt++) {
        int col = mt * 16 + fr;
        x[mt] = (col < Ll) ? 0.1f * acc[mt][r2] : -INFINITY;
      }
      float mx = x[0];
#pragma unroll
      for (int mt = 1; mt < 6; mt++) mx = fmaxf(mx, x[mt]);
      mx = fmaxf(mx, __shfl_xor(mx, 1));
      mx = fmaxf(mx, __shfl_xor(mx, 2));
      mx = fmaxf(mx, __shfl_xor(mx, 4));
      mx = fmaxf(mx, __shfl_xor(mx, 8));
      float e[6]; float s = 0.f;
#pragma unroll
      for (int mt = 0; mt < 6; mt++) { e[mt] = __expf(x[mt] - mx); s += e[mt]; }
      s += __shfl_xor(s, 1); s += __shfl_xor(s, 2);
      s += __shfl_xor(s, 4); s += __shfl_xor(s, 8);
      float inv = 1.f / s;
      if (l < Ll) {
#pragma unroll
        for (int mt = 0; mt < 6; mt++) colpart[mt] += e[mt] * inv;
      }
    }
#pragma unroll
    for (int mt = 0; mt < 6; mt++) {
      colpart[mt] += __shfl_xor(colpart[mt], 16);
      colpart[mt] += __shfl_xor(colpart[mt], 32);
    }
    if (lane < 16) {
#pragma unroll
      for (int mt = 0; mt < 6; mt++) atomicAdd(&wsum[mt * 16 + fr], colpart[mt]);
    }
  }
  __syncthreads();
  for (int i = tid; i < 304; i += 512) {
    float s = 0.f;
    if (i < Dd) {
#pragma unroll 15
      for (int m = 0; m < Ll; m++)
        s += wsum[m] * bf2f(Xs[(m * 640 + ((i * 2) ^ ((m & 7) << 4))) >> 1]);
    }
    r_all[(size_t)bid * 304 + i] = s;
  }
}

// ---------------- generic f32 GEMM ----------------
__global__ __launch_bounds__(256) void k_gemm_bt(
    const float* __restrict__ A, int lda, const float* __restrict__ W, int ldw,
    const float* __restrict__ bias, const float* __restrict__ res, int ldres,
    float* __restrict__ C, int ldc, int Mdim, int Ndim, int Kdim) {
  __shared__ float As[16][68];
  __shared__ float Bs[16][68];
  int m0 = blockIdx.x * 64, n0 = blockIdx.y * 64;
  int tx = threadIdx.x & 15, ty = threadIdx.x >> 4;
  float acc[4][4];
#pragma unroll
  for (int i = 0; i < 4; i++)
#pragma unroll
    for (int j = 0; j < 4; j++) acc[i][j] = 0.f;
  int r = threadIdx.x >> 2;
  int kq = (threadIdx.x & 3) << 2;
  for (int k0 = 0; k0 < Kdim; k0 += 16) {
    {
      int gm = m0 + r;
      float4 v = {0.f, 0.f, 0.f, 0.f};
      if (gm < Mdim) v = *(const float4*)(A + (size_t)gm * lda + k0 + kq);
      As[kq + 0][r] = v.x; As[kq + 1][r] = v.y; As[kq + 2][r] = v.z; As[kq + 3][r] = v.w;
    }
    {
      int gn = n0 + r;
      float4 v = {0.f, 0.f, 0.f, 0.f};
      if (gn < Ndim) v = *(const float4*)(W + (size_t)gn * ldw + k0 + kq);
      Bs[kq + 0][r] = v.x; Bs[kq + 1][r] = v.y; Bs[kq + 2][r] = v.z; Bs[kq + 3][r] = v.w;
    }
    __syncthreads();
#pragma unroll
    for (int kk = 0; kk < 16; kk++) {
      float4 av = *(const float4*)&As[kk][ty * 4];
      float4 bv = *(const float4*)&Bs[kk][tx * 4];
      acc[0][0] += av.x * bv.x; acc[0][1] += av.x * bv.y; acc[0][2] += av.x * bv.z; acc[0][3] += av.x * bv.w;
      acc[1][0] += av.y * bv.x; acc[1][1] += av.y * bv.y; acc[1][2] += av.y * bv.z; acc[1][3] += av.y * bv.w;
      acc[2][0] += av.z * bv.x; acc[2][1] += av.z * bv.y; acc[2][2] += av.z * bv.z; acc[2][3] += av.z * bv.w;
      acc[3][0] += av.w * bv.x; acc[3][1] += av.w * bv.y; acc[3][2] += av.w * bv.z; acc[3][3] += av.w * bv.w;
    }
    __syncthreads();
  }
#pragma unroll
  for (int i = 0; i < 4; i++) {
    int gm = m0 + ty * 4 + i;
    if (gm >= Mdim) continue;
#pragma unroll
    for (int j = 0; j < 4; j++) {
      int gn = n0 + tx * 4 + j;
      if (gn >= Ndim) continue;
      float v = acc[i][j];
      if (bias) v += bias[gn];
      if (res) v += res[(size_t)gm * ldres + gn];
      C[(size_t)gm * ldc + gn] = v;
    }
  }
}

// ---------------- normalize hrev rows -> bf16 ----------------
__global__ __launch_bounds__(256) void k_norm(const float* __restrict__ hrev,
                                              unsigned short* __restrict__ Hn) {
  int row = blockIdx.x * 4 + (threadIdx.x >> 6);
  int lane = threadIdx.x & 63;
  float v[5]; float ss = 0.f;
#pragma unroll
  for (int j = 0; j < 5; j++) {
    int i = lane + j * 64;
    float x = (i < Dd) ? hrev[(size_t)row * 304 + i] : 0.f;
    v[j] = x; ss += x * x;
  }
#pragma unroll
  for (int o = 32; o; o >>= 1) ss += __shfl_xor(ss, o);
  float inv = (ss > 0.f) ? rsqrtf(ss) : 0.f;
#pragma unroll
  for (int j = 0; j < 5; j++) {
    int i = lane + j * 64;
    if (i < DP) Hn[(size_t)row * DP + i] = f2bf(v[j] * inv);
  }
}

// ---------------- cosine gram + masked double softmax ----------------
__global__ __launch_bounds__(64) void k_simgram(
    const unsigned short* __restrict__ Hn, const int* __restrict__ adj,
    float* __restrict__ simin, float* __restrict__ simout) {
  int b = blockIdx.x, rt = blockIdx.y;
  int lane = threadIdx.x;
  int fr = lane & 15, kg = lane >> 4;
  const unsigned short* Hb = Hn + (size_t)b * Nn * DP;
  int ar = rt * 16 + fr;
  short8v zerov;
#pragma unroll
  for (int q = 0; q < 8; q++) zerov[q] = 0;
  f32x4 acc[7];
#pragma unroll
  for (int mt = 0; mt < 7; mt++) acc[mt] = (f32x4){0.f, 0.f, 0.f, 0.f};
#pragma unroll
  for (int ks = 0; ks < 10; ks++) {
    int koff = ks * 32 + kg * 8;
    short8v a = (ar < Nn) ? *(const short8v*)(Hb + (size_t)ar * DP + koff) : zerov;
#pragma unroll
    for (int mt = 0; mt < 7; mt++) {
      int br = mt * 16 + fr;
      short8v bb = (br < Nn) ? *(const short8v*)(Hb + (size_t)br * DP + koff) : zerov;
      acc[mt] = __builtin_amdgcn_mfma_f32_16x16x32_bf16(a, bb, acc[mt], 0, 0, 0);
    }
  }
  const int* adjb = adj + (size_t)b * Nn * 2 * Nn;
#pragma unroll
  for (int which = 0; which < 2; which++) {
    float* dst = which ? simout : simin;
#pragma unroll
    for (int r2 = 0; r2 < 4; r2++) {
      int l = rt * 16 + kg * 4 + r2;
      bool lv = l < Nn;
      float x[7];
#pragma unroll
      for (int mt = 0; mt < 7; mt++) {
        int col = mt * 16 + fr;
        bool cvd = col < Nn;
        int am = (lv && cvd) ? adjb[l * (2 * Nn) + which * Nn + col] : 0;
        x[mt] = cvd ? ((am > 0) ? acc[mt][r2] : -9e15f) : -INFINITY;
      }
      float mx = x[0];
#pragma unroll
      for (int mt = 1; mt < 7; mt++) mx = fmaxf(mx, x[mt]);
      mx = fmaxf(mx, __shfl_xor(mx, 1));
      mx = fmaxf(mx, __shfl_xor(mx, 2));
      mx = fmaxf(mx, __shfl_xor(mx, 4));
      mx = fmaxf(mx, __shfl_xor(mx, 8));
      float e[7]; float s = 0.f;
#pragma unroll
      for (int mt = 0; mt < 7; mt++) { e[mt] = __expf(x[mt] - mx); s += e[mt]; }
      s += __shfl_xor(s, 1); s += __shfl_xor(s, 2);
      s += __shfl_xor(s, 4); s += __shfl_xor(s, 8);
      float inv = 1.f / s;
      if (lv) {
#pragma unroll
        for (int mt = 0; mt < 7; mt++) {
          int col = mt * 16 + fr;
          if (col < Nn) dst[((size_t)(b * Nn + l)) * Nn + col] = e[mt] * inv;
        }
      }
    }
  }
}

// ---------------- final mix ----------------
__global__ __launch_bounds__(256) void k_mixout(
    const float* __restrict__ simin, const float* __restrict__ simout,
    const float* __restrict__ P, const float* __restrict__ dvec,
    float* __restrict__ out) {
  __shared__ float si[Nn], so[Nn];
  int bn = blockIdx.x, h = threadIdx.x, b = bn / Nn;
  if (h < Nn) {
    si[h] = simin[(size_t)bn * Nn + h];
    so[h] = simout[(size_t)bn * Nn + h];
  }
  __syncthreads();
  const float* Pb = P + (size_t)b * Nn * 512;
  float acc = dvec[h];
#pragma unroll 10
  for (int m = 0; m < Nn; m++)
    acc += si[m] * Pb[m * 512 + h] + so[m] * Pb[m * 512 + 256 + h];
  out[(size_t)bn * 256 + h] = acc;
}

extern "C" void kernel_launch(void* const* d_in, const int* in_sizes, int n_in,
                              void* d_out, int out_size, void* d_ws, size_t ws_size,
                              hipStream_t stream) {
  (void)in_sizes; (void)n_in; (void)out_size;
  const float* h_local = (const float*)d_in[0];
  const float* items   = (const float*)d_in[1];
  const int*   adj     = (const int*)d_in[2];
  const float* bn_g  = (const float*)d_in[4];
  const float* bn_b  = (const float*)d_in[5];
  const float* W_q = (const float*)d_in[6];   const float* b_q = (const float*)d_in[7];
  const float* W_k = (const float*)d_in[8];   const float* b_k = (const float*)d_in[9];
  const float* W_v = (const float*)d_in[10];  const float* b_v = (const float*)d_in[11];
  const float* W_f = (const float*)d_in[12];  const float* b_f = (const float*)d_in[13];
  const float* W_fc = (const float*)d_in[14]; const float* b_fc = (const float*)d_in[15];
  const float* W_in = (const float*)d_in[16]; const float* b_in = (const float*)d_in[17];
  const float* W_out = (const float*)d_in[18]; const float* b_out = (const float*)d_in[19];
  const float* b_iah = (const float*)d_in[20]; const float* b_oah = (const float*)d_in[21];
  const float* W_io = (const float*)d_in[22];  const float* b_io = (const float*)d_in[23];
  float* out = (float*)d_out;

  char* w = (char*)d_ws;
  auto alloc = [&](size_t bytes) { char* p = w; w += (bytes + 255) & ~(size_t)255; return p; };
  unsigned short* Mb = (unsigned short*)alloc((size_t)DP * DP * 2);
  float* G      = (float*)alloc((size_t)Dd * 304 * 4);
  float* bias2  = (float*)alloc(304 * 4);
  float* Tbuf   = (float*)alloc((size_t)512 * 256 * 4);
  float* Bcat   = (float*)alloc((size_t)512 * 256 * 4);
  float* dvec   = (float*)alloc(256 * 4);
  float* r_all  = (float*)alloc((size_t)NBLK * 304 * 4);
  float* colsum = (float*)alloc((size_t)NBLK * 304 * 4);
  float* hrev   = (float*)alloc((size_t)NBLK * 304 * 4);
  unsigned short* Hn = (unsigned short*)alloc((size_t)NBLK * DP * 2);
  float* simin  = (float*)alloc((size_t)NBLK * Nn * 4);
  float* simout = (float*)alloc((size_t)NBLK * Nn * 4);
  float* P      = (float*)alloc((size_t)NBLK * 512 * 4);
  unsigned short* ZT = (unsigned short*)alloc((size_t)NBLK * LP * DP * 2);  // 98.3 MB
  const bool big = ((size_t)(w - (char*)d_ws)) <= ws_size;

  k_setup<<<758, 256, 0, stream>>>(W_q, W_k, b_q, b_k, W_f, W_v, b_v, b_f,
                                   Mb, G, bias2);
  if (big) {
    k_zt<<<NBLK, 512, 0, stream>>>(items, Mb, ZT, colsum);
    k_attn2<<<NBLK, 384, 0, stream>>>(items, ZT, r_all);
  } else {
    k_attn<<<NBLK, 512, 0, stream>>>(items, Mb, r_all, colsum);
  }

  {
    dim3 g(4, 4, 2);
    k_mm256<<<g, 256, 0, stream>>>(W_in, W_out, 256, W_fc, W_fc, 256, Tbuf, 256, nullptr);
    k_mm256<<<g, 256, 0, stream>>>(W_io, W_io + 256, 512, Tbuf, Tbuf + 256 * 256, 256,
                                   Bcat, 256, bn_g);
  }
  k_vecd<<<1, 256, 0, stream>>>(W_fc, b_fc, bn_b, W_in, b_in, b_iah,
                                W_out, b_out, b_oah, W_io, b_io, dvec);
  {
    dim3 g(25, 8);
    k_gemm_bt<<<g, 256, 0, stream>>>(h_local, 256, Bcat, 256, nullptr, nullptr, 0,
                                     P, 512, NBLK, 512, 256);
  }
  {
    dim3 g(25, 5);
    k_gemm_bt<<<g, 256, 0, stream>>>(r_all, 304, G, 304, bias2, colsum, 304,
                                     hrev, 304, NBLK, 300, 304);
  }
  k_norm<<<NBLK / 4, 256, 0, stream>>>(hrev, Hn);
  {
    dim3 g(Bb, 7);
    k_simgram<<<g, 64, 0, stream>>>(Hn, adj, simin, simout);
  }
  k_mixout<<<NBLK, 256, 0, stream>>>(simin, simout, P, dvec, out);
}